// Round 7
// baseline (513.626 us; speedup 1.0000x reference)
//
#include <hip/hip_runtime.h>

// GraphSAGE link predictor, bf16-MFMA edition.
//   h = relu( mean_agg(x)@w1l.T + b1 + x@w1r.T )
//   z = mean_agg(h)@w2l.T + b2 + h@w2r.T
//   out[e] = dot(z[src[e]], z[dst[e]])
//
// R4: XCD-partitioned CSR build. R5: bf16 MFMA GEMMs. R6: bf16 z + fused
//     layer-1 (agg-then-project, K=256 single GEMM).
// R7: R6 counters: fill_csr 75us, WRITE=72MB for 6.4MB payload — 11x write
//     amplification: streaming edge reads (12.8MB/XCD) evict partially-filled
//     dirty csr lines from the 4MB L2 ~11 times each. Fix: nontemporal (nt)
//     loads for zero-reuse streams (edge index in count/fill/decode, csr_src
//     in agg) so L2 keeps only the scattered-write/gather working sets.
//
// edge_index arrives as int32 (harness converts int64 inputs).

#define IN_C      128
#define HID_C     128
#define OUT_C     64
#define NPART     8
#define SLICE_E   4096

typedef unsigned short u16;
typedef __attribute__((ext_vector_type(8))) __bf16 bf16x8;
typedef __attribute__((ext_vector_type(4))) float f32x4;

__device__ inline u16 f2bf(float f) {                 // RNE f32 -> bf16
    unsigned u = __float_as_uint(f);
    u += 0x7fff + ((u >> 16) & 1);
    return (u16)(u >> 16);
}
__device__ inline float bflo(unsigned v) { return __uint_as_float(v << 16); }
__device__ inline float bfhi(unsigned v) { return __uint_as_float(v & 0xffff0000u); }

// ---------------------------------------------------------------- CSR build
__global__ __launch_bounds__(256) void count_deg(const int* __restrict__ ei,
                                                 int* __restrict__ cnt, int E, int n) {
    const int range = blockIdx.x & (NPART - 1);
    const int slice = blockIdx.x >> 3;
    const int nr = (n + NPART - 1) / NPART;
    const int lo = range * nr;
    const int hi = min(n, lo + nr);
    const int e1 = min(E, (slice + 1) * SLICE_E);
    for (int e = slice * SLICE_E + threadIdx.x; e < e1; e += 256) {
        int d = __builtin_nontemporal_load(ei + (size_t)E + e);
        if (d >= lo && d < hi) atomicAdd(&cnt[d], 1);
    }
}

__global__ __launch_bounds__(256) void scan_partial(const int* __restrict__ cnt,
                                                    int* __restrict__ tile_sums, int n) {
    __shared__ int sd[256];
    int t = threadIdx.x;
    int base = blockIdx.x * 1024;
    int s = 0;
#pragma unroll
    for (int i = 0; i < 4; ++i) {
        int idx = base + t * 4 + i;
        if (idx < n) s += cnt[idx];
    }
    sd[t] = s;
    __syncthreads();
    for (int o = 128; o > 0; o >>= 1) {
        if (t < o) sd[t] += sd[t + o];
        __syncthreads();
    }
    if (t == 0) tile_sums[blockIdx.x] = sd[0];
}

__global__ __launch_bounds__(256) void scan_tiles(int* __restrict__ tile_sums, int nt) {
    __shared__ int sd[256];
    int t = threadIdx.x;
    int v = (t < nt) ? tile_sums[t] : 0;
    sd[t] = v;
    __syncthreads();
    for (int o = 1; o < 256; o <<= 1) {
        int vv = 0;
        if (t >= o) vv = sd[t - o];
        __syncthreads();
        sd[t] += vv;
        __syncthreads();
    }
    if (t < nt) tile_sums[t] = sd[t] - v;   // exclusive
}

__global__ __launch_bounds__(256) void scan_final(const int* __restrict__ cnt,
                                                  const int* __restrict__ tile_sums,
                                                  int* __restrict__ row_ptr,
                                                  int* __restrict__ cursor,
                                                  float* __restrict__ inv_deg,
                                                  int n, int E) {
    __shared__ int sd[256];
    int t = threadIdx.x;
    int base = blockIdx.x * 1024;
    int loc[4];
    int s = 0;
#pragma unroll
    for (int i = 0; i < 4; ++i) {
        int idx = base + t * 4 + i;
        loc[i] = (idx < n) ? cnt[idx] : 0;
        s += loc[i];
    }
    int own = s;
    sd[t] = s;
    __syncthreads();
    for (int o = 1; o < 256; o <<= 1) {
        int vv = 0;
        if (t >= o) vv = sd[t - o];
        __syncthreads();
        sd[t] += vv;
        __syncthreads();
    }
    int off = tile_sums[blockIdx.x] + sd[t] - own;
#pragma unroll
    for (int i = 0; i < 4; ++i) {
        int idx = base + t * 4 + i;
        if (idx < n) {
            row_ptr[idx] = off;
            cursor[idx]  = off;
            inv_deg[idx] = 1.0f / (float)max(loc[i], 1);
            off += loc[i];
        }
    }
    if (blockIdx.x == 0 && t == 0) row_ptr[n] = E;
}

__global__ __launch_bounds__(256) void fill_csr(const int* __restrict__ ei,
                                                int* __restrict__ cursor,
                                                int* __restrict__ csr_src, int E, int n) {
    const int range = blockIdx.x & (NPART - 1);
    const int slice = blockIdx.x >> 3;
    const int nr = (n + NPART - 1) / NPART;
    const int lo = range * nr;
    const int hi = min(n, lo + nr);
    const int e1 = min(E, (slice + 1) * SLICE_E);
    for (int e = slice * SLICE_E + threadIdx.x; e < e1; e += 256) {
        int d = __builtin_nontemporal_load(ei + (size_t)E + e);
        if (d >= lo && d < hi) {
            int s = __builtin_nontemporal_load(ei + e);
            if ((unsigned)s < (unsigned)n) {
                int pos = atomicAdd(&cursor[d], 1);
                csr_src[pos] = s;
            }
        }
    }
}

// ---------------------------------------------------------------- converts
__global__ __launch_bounds__(256) void cvt_x(const float* __restrict__ in,
                                             u16* __restrict__ outb, int n4) {
    int i = blockIdx.x * 256 + threadIdx.x;
    if (i >= n4) return;
    float4 v = ((const float4*)in)[i];
    ushort4 o;
    o.x = f2bf(v.x); o.y = f2bf(v.y); o.z = f2bf(v.z); o.w = f2bf(v.w);
    ((ushort4*)outb)[i] = o;
}

// Wb1[c][0:128]=w1l[c], Wb1[c][128:256]=w1r[c]  -> [128][256] bf16
// Wb2 = cat(w2l,w2r)                             -> [128][128] bf16
__global__ __launch_bounds__(256) void cvt_w(const float* __restrict__ w1l,
                                             const float* __restrict__ w1r,
                                             const float* __restrict__ w2l,
                                             const float* __restrict__ w2r,
                                             u16* __restrict__ Wb1,
                                             u16* __restrict__ Wb2) {
    int i = blockIdx.x * 256 + threadIdx.x;
    if (i < 32768) {
        int c = i >> 8, k = i & 255;
        float v = (k < 128) ? w1l[c * 128 + k] : w1r[c * 128 + (k - 128)];
        Wb1[i] = f2bf(v);
    } else if (i < 49152) {
        int j = i - 32768;
        float v = (j < 8192) ? w2l[j] : w2r[j - 8192];
        Wb2[j] = f2bf(v);
    }
}

// ---------------------------------------------------------------- fused layer-1 GEMM
// h = relu([A0|A1] @ W.T + b), A0/A1 [n][128] bf16, W [128][256] bf16 -> h [n][128] bf16
// Frag facts (m89/m120): A[m=lane&15][k=quad*8+j], B[k=quad*8+j][n=lane&15],
// D: col=lane&15, row=quad*4+reg. Both frags = 8 contiguous k's of a row.
__global__ __launch_bounds__(256) void gemm_l1(const u16* __restrict__ A0,
                                               const u16* __restrict__ A1,
                                               const u16* __restrict__ Wb,
                                               const float* __restrict__ bias,
                                               u16* __restrict__ outp, int nrows) {
    constexpr int K    = 256;
    constexpr int COLS = 128;
    constexpr int KS   = K / 32;             // 8
    constexpr int NCT  = COLS / 16;          // 8
    constexpr int WROW = K + 8;
    __shared__ u16 wl[COLS * WROW];          // 67.6 KB

    const int t = threadIdx.x;
    for (int i = t; i < COLS * (K / 8); i += 256) {
        int r = i >> 5, p = i & 31;
        *(uint4*)&wl[r * WROW + p * 8] = *(const uint4*)&Wb[(size_t)r * K + p * 8];
    }
    __syncthreads();

    const int wv    = t >> 6;
    const int lane  = t & 63;
    const int cl    = lane & 15;
    const int quad  = lane >> 4;
    const int rbase = blockIdx.x * 128 + wv * 32;

    bf16x8 afrag[2][KS];
#pragma unroll
    for (int tile = 0; tile < 2; ++tile) {
        int r = min(rbase + tile * 16 + cl, nrows - 1);
        const u16* s0 = A0 + (size_t)r * 128 + quad * 8;
        const u16* s1 = A1 + (size_t)r * 128 + quad * 8;
#pragma unroll
        for (int ks = 0; ks < 4; ++ks) {
            afrag[tile][ks]     = *(const bf16x8*)(s0 + ks * 32);
            afrag[tile][4 + ks] = *(const bf16x8*)(s1 + ks * 32);
        }
    }

#pragma unroll
    for (int ct = 0; ct < NCT; ++ct) {
        f32x4 acc0 = {0.f, 0.f, 0.f, 0.f};
        f32x4 acc1 = {0.f, 0.f, 0.f, 0.f};
        const u16* wp = &wl[(ct * 16 + cl) * WROW + quad * 8];
#pragma unroll
        for (int ks = 0; ks < KS; ++ks) {
            bf16x8 bfrag = *(const bf16x8*)(wp + ks * 32);
            acc0 = __builtin_amdgcn_mfma_f32_16x16x32_bf16(afrag[0][ks], bfrag, acc0, 0, 0, 0);
            acc1 = __builtin_amdgcn_mfma_f32_16x16x32_bf16(afrag[1][ks], bfrag, acc1, 0, 0, 0);
        }
        int gc = ct * 16 + cl;
        float bv = bias[gc];
#pragma unroll
        for (int tile = 0; tile < 2; ++tile) {
            f32x4 a = tile ? acc1 : acc0;
#pragma unroll
            for (int r = 0; r < 4; ++r) {
                int row = rbase + tile * 16 + quad * 4 + r;
                if (row < nrows)
                    outp[(size_t)row * COLS + gc] = f2bf(fmaxf(a[r] + bv, 0.f));
            }
        }
    }
}

// ---------------------------------------------------------------- dual GEMM (layer 2)
// [outA | outB](bf16) = xb @ Wb.T ; outB += bias. Wb [2*COLS][K] bf16.
template <int K, int COLS>
__global__ __launch_bounds__(256) void gemm_mfma(const u16* __restrict__ xb,
                                                 const u16* __restrict__ Wb,
                                                 const float* __restrict__ bias,
                                                 u16* __restrict__ outA,
                                                 u16* __restrict__ outB,
                                                 int nrows) {
    constexpr int NCOL = 2 * COLS;
    constexpr int NCT  = NCOL / 16;
    constexpr int KS   = K / 32;
    constexpr int WROW = K + 8;
    __shared__ u16 wl[NCOL * WROW];

    const int t = threadIdx.x;
    for (int i = t; i < NCOL * (K / 8); i += 256) {
        int r = i / (K / 8), p = i % (K / 8);
        *(uint4*)&wl[r * WROW + p * 8] = *(const uint4*)&Wb[(size_t)r * K + p * 8];
    }
    __syncthreads();

    const int wv    = t >> 6;
    const int lane  = t & 63;
    const int cl    = lane & 15;
    const int quad  = lane >> 4;
    const int rbase = blockIdx.x * 128 + wv * 32;

    bf16x8 afrag[2][KS];
#pragma unroll
    for (int tile = 0; tile < 2; ++tile) {
        int r = rbase + tile * 16 + cl;
        const u16* src = xb + (size_t)min(r, nrows - 1) * K + quad * 8;
#pragma unroll
        for (int ks = 0; ks < KS; ++ks)
            afrag[tile][ks] = *(const bf16x8*)(src + ks * 32);
    }

#pragma unroll
    for (int ct = 0; ct < NCT; ++ct) {
        f32x4 acc0 = {0.f, 0.f, 0.f, 0.f};
        f32x4 acc1 = {0.f, 0.f, 0.f, 0.f};
        const u16* wp = &wl[(ct * 16 + cl) * WROW + quad * 8];
#pragma unroll
        for (int ks = 0; ks < KS; ++ks) {
            bf16x8 bfrag = *(const bf16x8*)(wp + ks * 32);
            acc0 = __builtin_amdgcn_mfma_f32_16x16x32_bf16(afrag[0][ks], bfrag, acc0, 0, 0, 0);
            acc1 = __builtin_amdgcn_mfma_f32_16x16x32_bf16(afrag[1][ks], bfrag, acc1, 0, 0, 0);
        }
        int gc = ct * 16 + cl;
        bool isA = gc < COLS;
        float bv = isA ? 0.f : bias[gc - COLS];
        u16* dst = isA ? (outA + gc) : (outB + (gc - COLS));
#pragma unroll
        for (int tile = 0; tile < 2; ++tile) {
            f32x4 a = tile ? acc1 : acc0;
#pragma unroll
            for (int r = 0; r < 4; ++r) {
                int row = rbase + tile * 16 + quad * 4 + r;
                if (row < nrows) dst[(size_t)row * COLS] = f2bf(a[r] + bv);
            }
        }
    }
}

// ---------------------------------------------------------------- aggregate
// out[n] = (sum_{s in csr[n]} gl[s]) * inv_deg[n]  [+ other[n]] ; bf16 in/out.
template <int C, bool HAS_OTHER>
__global__ __launch_bounds__(256) void agg_bf(const u16* __restrict__ gl,
                                              const u16* __restrict__ other,
                                              const int* __restrict__ row_ptr,
                                              const int* __restrict__ csr_src,
                                              const float* __restrict__ inv_deg,
                                              u16* __restrict__ outp, int n) {
    constexpr int G = C / 8;                 // lanes per node
    int t = threadIdx.x;
    int node = blockIdx.x * (256 / G) + t / G;
    int l = t % G;
    if (node >= n) return;

    int p0 = row_ptr[node], p1 = row_ptr[node + 1];
    float a[8] = {0.f, 0.f, 0.f, 0.f, 0.f, 0.f, 0.f, 0.f};
    const size_t coff = (size_t)l * 8;
    for (int p = p0; p < p1; ++p) {
        int s = __builtin_nontemporal_load(csr_src + p);
        uint4 v = *(const uint4*)(gl + (size_t)s * C + coff);
        a[0] += bflo(v.x); a[1] += bfhi(v.x);
        a[2] += bflo(v.y); a[3] += bfhi(v.y);
        a[4] += bflo(v.z); a[5] += bfhi(v.z);
        a[6] += bflo(v.w); a[7] += bfhi(v.w);
    }
    float id = inv_deg[node];
    float r[8];
    if (HAS_OTHER) {
        uint4 o = *(const uint4*)(other + (size_t)node * C + coff);
        r[0] = fmaf(a[0], id, bflo(o.x)); r[1] = fmaf(a[1], id, bfhi(o.x));
        r[2] = fmaf(a[2], id, bflo(o.y)); r[3] = fmaf(a[3], id, bfhi(o.y));
        r[4] = fmaf(a[4], id, bflo(o.z)); r[5] = fmaf(a[5], id, bfhi(o.z));
        r[6] = fmaf(a[6], id, bflo(o.w)); r[7] = fmaf(a[7], id, bfhi(o.w));
    } else {
#pragma unroll
        for (int j = 0; j < 8; ++j) r[j] = a[j] * id;
    }
    uint4 w;
    w.x = (unsigned)f2bf(r[0]) | ((unsigned)f2bf(r[1]) << 16);
    w.y = (unsigned)f2bf(r[2]) | ((unsigned)f2bf(r[3]) << 16);
    w.z = (unsigned)f2bf(r[4]) | ((unsigned)f2bf(r[5]) << 16);
    w.w = (unsigned)f2bf(r[6]) | ((unsigned)f2bf(r[7]) << 16);
    *(uint4*)(outp + (size_t)node * C + coff) = w;
}

// ---------------------------------------------------------------- decode (bf16 z)
__global__ __launch_bounds__(256) void decode(const u16* __restrict__ z,
                                              const int* __restrict__ ei,
                                              float* __restrict__ out, int E, int n) {
    int t = blockIdx.x * 256 + threadIdx.x;
    int e = t >> 3, l = t & 7;
    if (e >= E) return;
    int s = __builtin_nontemporal_load(ei + e);
    int d = __builtin_nontemporal_load(ei + (size_t)E + e);
    float p = 0.f;
    if ((unsigned)s < (unsigned)n && (unsigned)d < (unsigned)n) {
        uint4 a = *(const uint4*)(z + (size_t)s * OUT_C + l * 8);
        uint4 b = *(const uint4*)(z + (size_t)d * OUT_C + l * 8);
        p  = bflo(a.x) * bflo(b.x) + bfhi(a.x) * bfhi(b.x);
        p += bflo(a.y) * bflo(b.y) + bfhi(a.y) * bfhi(b.y);
        p += bflo(a.z) * bflo(b.z) + bfhi(a.z) * bfhi(b.z);
        p += bflo(a.w) * bflo(b.w) + bfhi(a.w) * bfhi(b.w);
    }
    p += __shfl_xor(p, 4);
    p += __shfl_xor(p, 2);
    p += __shfl_xor(p, 1);
    if (l == 0) out[e] = p;
}

// ---------------------------------------------------------------- launch
extern "C" void kernel_launch(void* const* d_in, const int* in_sizes, int n_in,
                              void* d_out, int out_size, void* d_ws, size_t ws_size,
                              hipStream_t stream) {
    const float* x   = (const float*)d_in[0];
    const int*   ei  = (const int*)d_in[1];
    const float* w1l = (const float*)d_in[2];
    const float* w1r = (const float*)d_in[3];
    const float* b1  = (const float*)d_in[4];
    const float* w2l = (const float*)d_in[5];
    const float* w2r = (const float*)d_in[6];
    const float* b2  = (const float*)d_in[7];
    float*       out = (float*)d_out;

    const int N = in_sizes[0] / IN_C;
    const int E = in_sizes[1] / 2;

    auto alignup = [](size_t v) { return (v + 255) & ~(size_t)255; };
    char* p = (char*)d_ws;
    int*   cnt       = (int*)p;   p += alignup((size_t)N * 4);
    int*   row_ptr   = (int*)p;   p += alignup((size_t)(N + 1) * 4);
    int*   cursor    = (int*)p;   p += alignup((size_t)N * 4);
    int*   tile_sums = (int*)p;   p += alignup((size_t)256 * 4);
    float* inv_deg   = (float*)p; p += alignup((size_t)N * 4);
    int*   csr_src   = (int*)p;   p += alignup((size_t)E * 4);
    u16*   Wb1       = (u16*)p;   p += alignup((size_t)HID_C * 2 * IN_C * 2);
    u16*   Wb2       = (u16*)p;   p += alignup((size_t)2 * OUT_C * HID_C * 2);
    u16*   xb        = (u16*)p;   p += alignup((size_t)N * IN_C * 2);
    u16*   ag1       = (u16*)p;   p += alignup((size_t)N * HID_C * 2);
    u16*   hb        = (u16*)p;   p += alignup((size_t)N * HID_C * 2);
    u16*   hlb       = (u16*)p;   p += alignup((size_t)N * OUT_C * 2);
    u16*   hrb       = (u16*)p;   p += alignup((size_t)N * OUT_C * 2);
    u16*   zb        = (u16*)p;   p += alignup((size_t)N * OUT_C * 2);

    const int nt = (N + 1023) / 1024;
    const int nslice = (E + SLICE_E - 1) / SLICE_E;

    // converts (independent of CSR)
    cvt_x<<<(N * IN_C / 4 + 255) / 256, 256, 0, stream>>>(x, xb, N * IN_C / 4);
    cvt_w<<<192, 256, 0, stream>>>(w1l, w1r, w2l, w2r, Wb1, Wb2);

    // CSR build (count/fill XCD-partitioned by dst range; nt edge reads)
    hipMemsetAsync(cnt, 0, (size_t)N * 4, stream);
    count_deg<<<nslice * NPART, 256, 0, stream>>>(ei, cnt, E, N);
    scan_partial<<<nt, 256, 0, stream>>>(cnt, tile_sums, N);
    scan_tiles<<<1, 256, 0, stream>>>(tile_sums, nt);
    scan_final<<<nt, 256, 0, stream>>>(cnt, tile_sums, row_ptr, cursor, inv_deg, N, E);
    fill_csr<<<nslice * NPART, 256, 0, stream>>>(ei, cursor, csr_src, E, N);

    const int rb = (N + 127) / 128;

    // ag1 = mean_agg(xb)
    agg_bf<HID_C, false><<<(N + 15) / 16, 256, 0, stream>>>(xb, nullptr, row_ptr,
                                                            csr_src, inv_deg, ag1, N);
    // h = relu([ag1|xb] @ [w1l|w1r].T + b1)
    gemm_l1<<<rb, 256, 0, stream>>>(ag1, xb, Wb1, b1, hb, N);

    // hl = h@w2l.T ; hr = h@w2r.T + b2
    gemm_mfma<HID_C, OUT_C><<<rb, 256, 0, stream>>>(hb, Wb2, b2, hlb, hrb, N);
    // z = agg(hl)/deg + hr  (bf16)
    agg_bf<OUT_C, true><<<(N + 31) / 32, 256, 0, stream>>>(hlb, hrb, row_ptr, csr_src,
                                                           inv_deg, zb, N);

    // decode (bf16 z)
    decode<<<((size_t)E * 8 + 255) / 256, 256, 0, stream>>>(zb, ei, out, E, N);
}